// Round 3
// baseline (1613.787 us; speedup 1.0000x reference)
//
#include <hip/hip_runtime.h>
#include <hip/hip_bf16.h>
#include <math.h>

#define B 4096
#define S 32
#define D 256
#define V 50257
#define N_ALIVE 100
#define K_PAD 128          // K=100 zero-padded to 128 (4 x mfma K=32)
#define V_PAD 50432        // 197 * 256

typedef __attribute__((ext_vector_type(8))) short short8;   // 8 bf16 (4 VGPRs)
typedef __attribute__((ext_vector_type(4))) float float4v;  // 4 fp32 acc

__device__ __forceinline__ short f2bf(float f) {
    __hip_bfloat16 h = __float2bfloat16(f);
    return *reinterpret_cast<short*>(&h);
}

// ---------------------------------------------------------------------------
// Kernel A: per-batch context pooling + RBF activations.
// Writes the bf16 A-matrix [B, K_PAD] (cols 100..127 zero).
// One block (256 threads = 4 waves) per batch row.
// ---------------------------------------------------------------------------
__global__ __launch_bounds__(256) void ctx_act_kernel(
    const int*   __restrict__ token_ids,   // [B,S]
    const float* __restrict__ te,          // [V,D]
    const float* __restrict__ pe,          // [S,D]
    const float* __restrict__ q,           // [D]
    const float* __restrict__ pos,         // [N,D]
    __hip_bfloat16* __restrict__ A)        // [B, K_PAD]
{
    __shared__ __align__(16) float s_emb[S][D];   // 32 KB
    __shared__ int   s_ids[S];
    __shared__ float s_scores[S];
    __shared__ float s_w[S];
    __shared__ __align__(16) float s_ctx[D];
    __shared__ float s_red[128];
    __shared__ float s_total;

    const int b    = blockIdx.x;
    const int tid  = threadIdx.x;
    const int lane = tid & 63;
    const int wave = tid >> 6;

    if (tid < S) s_ids[tid] = token_ids[b * S + tid];
    __syncthreads();

    // ---- embeds -> LDS + attention scores (wave w handles s = 8w..8w+7) ----
    const float4 qv = *(const float4*)(q + lane * 4);
    #pragma unroll
    for (int j = 0; j < 8; ++j) {
        const int s = wave * 8 + j;
        const float4 t4 = *(const float4*)(te + (size_t)s_ids[s] * D + lane * 4);
        const float4 p4 = *(const float4*)(pe + (size_t)s * D + lane * 4);
        float4 e4;
        e4.x = t4.x + p4.x; e4.y = t4.y + p4.y;
        e4.z = t4.z + p4.z; e4.w = t4.w + p4.w;
        *(float4*)&s_emb[s][lane * 4] = e4;
        float p = e4.x * qv.x + e4.y * qv.y + e4.z * qv.z + e4.w * qv.w;
        #pragma unroll
        for (int m = 32; m >= 1; m >>= 1) p += __shfl_xor(p, m);
        if (lane == 0) s_scores[s] = p * 0.0625f;   // 1/sqrt(256)
    }
    __syncthreads();

    // ---- softmax over S=32 (first 32 lanes of wave 0) ----
    if (tid < 32) {
        const float sc = s_scores[tid];
        float m = sc;
        #pragma unroll
        for (int k = 16; k >= 1; k >>= 1) m = fmaxf(m, __shfl_xor(m, k));
        const float e = expf(sc - m);
        float tot = e;
        #pragma unroll
        for (int k = 16; k >= 1; k >>= 1) tot += __shfl_xor(tot, k);
        s_w[tid] = e / tot;
    }
    __syncthreads();

    // ---- context: thread tid owns dim d = tid ----
    {
        float c = 0.f;
        #pragma unroll
        for (int s = 0; s < S; ++s) c += s_w[s] * s_emb[s][tid];
        s_ctx[tid] = c;
    }
    __syncthreads();

    // ---- RBF activations: thread n = tid (n < 100) ----
    float a = 0.f;
    if (tid < N_ALIVE) {
        const float4* p4 = (const float4*)(pos + (size_t)tid * D);
        const float4* c4 = (const float4*)s_ctx;
        float d2 = 0.f;
        #pragma unroll 8
        for (int dd = 0; dd < D / 4; ++dd) {
            const float4 cv = c4[dd];
            const float4 pv = p4[dd];
            const float dx = cv.x - pv.x;
            const float dy = cv.y - pv.y;
            const float dz = cv.z - pv.z;
            const float dw = cv.w - pv.w;
            d2 += dx * dx + dy * dy + dz * dz + dw * dw;
        }
        a = expf(-2.0f * d2);   // exp(-d2 / (2 * 0.5^2))
    }
    if (tid < 128) s_red[tid] = (tid < N_ALIVE) ? a : 0.f;
    __syncthreads();
    if (tid < 64) s_red[tid] += s_red[tid + 64];
    __syncthreads();
    if (tid < 64) {
        float v = s_red[tid];
        #pragma unroll
        for (int k = 32; k >= 1; k >>= 1) v += __shfl_xor(v, k);
        if (tid == 0) s_total = v;
    }
    __syncthreads();
    if (tid < K_PAD) {
        const float val = (tid < N_ALIVE) ? (a / (s_total + 1e-8f)) : 0.f;
        A[(size_t)b * K_PAD + tid] = __float2bfloat16(val);
    }
}

// ---------------------------------------------------------------------------
// Transpose/convert: Wt[v][k] = bf16(W[k][v]), zero-padded to [V_PAD, K_PAD].
// Coalesced W reads; stores packed into 2 x 16B per thread (was 16 x 2B).
// grid = (197, 8).
// ---------------------------------------------------------------------------
__global__ __launch_bounds__(256) void transpose_w(
    const float* __restrict__ W,            // [N_ALIVE, V]
    __hip_bfloat16* __restrict__ Wt)        // [V_PAD, K_PAD]
{
    const int v  = blockIdx.x * 256 + threadIdx.x;   // < V_PAD by grid
    const int k0 = blockIdx.y * 16;
    short8 p0, p1;
    #pragma unroll
    for (int kk = 0; kk < 8; ++kk) {
        const int k = k0 + kk;
        p0[kk] = f2bf((v < V && k < N_ALIVE) ? W[(size_t)k * V + v] : 0.f);
    }
    #pragma unroll
    for (int kk = 0; kk < 8; ++kk) {
        const int k = k0 + 8 + kk;
        p1[kk] = f2bf((v < V && k < N_ALIVE) ? W[(size_t)k * V + v] : 0.f);
    }
    short* dst = (short*)Wt + (size_t)v * K_PAD + k0;   // 32B-aligned
    *(short8*)dst       = p0;
    *(short8*)(dst + 8) = p1;
}

// ---------------------------------------------------------------------------
// Kernel B: out[B,V] = A[B,K_PAD] @ Wt[V_PAD,K_PAD]^T via bf16 MFMA.
// Block = 256 threads (4 waves). Block tile: 64 M-rows x 256 N-cols.
// A-tile staged in LDS (272B padded row stride); a-frags re-read per it from
// LDS so live VGPRs stay ~70 -> high occupancy. Nontemporal C stores.
// mfma_f32_16x16x32_bf16 layouts:
//   A: m = lane&15, k = (lane>>4)*8 + j
//   B: n = lane&15, k = (lane>>4)*8 + j
//   C/D: col = lane&15, row = (lane>>4)*4 + reg
// ---------------------------------------------------------------------------
#define MT 4
#define NITER 4
#define LDA 136   // shorts per LDS row (272B = 17*16B, keeps b128 aligned)

__global__ __launch_bounds__(256) void gemm_mfma(
    const __hip_bfloat16* __restrict__ A,    // [B, K_PAD]
    const __hip_bfloat16* __restrict__ Wt,   // [V_PAD, K_PAD]
    float* __restrict__ out)                 // [B, V]
{
    __shared__ __align__(16) short s_a[64 * LDA];   // 17 KB

    const int tid  = threadIdx.x;
    const int lane = tid & 63;
    const int wave = tid >> 6;
    const int quad = lane >> 4;
    const int l16  = lane & 15;
    const int y0   = blockIdx.y * (MT * 16);
    const int x0   = blockIdx.x * 256;

    // ---- stage A tile (64 rows x 256B) into LDS ----
    #pragma unroll
    for (int i = 0; i < 4; ++i) {
        const int idx  = i * 256 + tid;      // 0..1023
        const int row  = idx >> 4;           // 0..63
        const int chnk = idx & 15;           // 16B chunks
        const short8 vdat = *(const short8*)((const short*)A +
                              (size_t)(y0 + row) * K_PAD + chnk * 8);
        *(short8*)(s_a + row * LDA + chnk * 8) = vdat;
    }
    __syncthreads();

    for (int it = 0; it < NITER; ++it) {
        const int col = x0 + it * 64 + wave * 16 + l16;
        const short* bp = (const short*)Wt + (size_t)col * K_PAD;
        short8 b_frag[4];
        #pragma unroll
        for (int ks = 0; ks < 4; ++ks)
            b_frag[ks] = *(const short8*)(bp + ks * 32 + quad * 8);

        #pragma unroll
        for (int mt = 0; mt < MT; ++mt) {
            const short* ap = s_a + (mt * 16 + l16) * LDA + quad * 8;
            float4v acc = {0.f, 0.f, 0.f, 0.f};
            #pragma unroll
            for (int ks = 0; ks < 4; ++ks) {
                const short8 a_frag = *(const short8*)(ap + ks * 32);
                acc = __builtin_amdgcn_mfma_f32_16x16x32_bf16(
                          a_frag, b_frag[ks], acc, 0, 0, 0);
            }
            if (col < V) {
                #pragma unroll
                for (int r = 0; r < 4; ++r)
                    __builtin_nontemporal_store(acc[r],
                        &out[(size_t)(y0 + mt * 16 + quad * 4 + r) * V + col]);
            }
        }
    }
}

// ---------------------------------------------------------------------------
// Fallback (ws too small for Wt): fp32 VALU, TB=16 rows in VGPRs (no spill).
// ---------------------------------------------------------------------------
__global__ __launch_bounds__(256) void logits_fallback(
    const __hip_bfloat16* __restrict__ A,   // [B, K_PAD]
    const float* __restrict__ W,            // [N_ALIVE, V]
    float* __restrict__ out)                // [B, V]
{
    const int v  = blockIdx.x * 256 + threadIdx.x;
    const int b0 = blockIdx.y * 16;
    const bool valid = (v < V);

    float acc[16];
    #pragma unroll
    for (int i = 0; i < 16; ++i) acc[i] = 0.f;

    for (int k = 0; k < N_ALIVE; ++k) {
        const float w = valid ? W[(size_t)k * V + v] : 0.f;
        #pragma unroll
        for (int i = 0; i < 16; ++i) {
            const float a = __bfloat162float(A[(size_t)(b0 + i) * K_PAD + k]);
            acc[i] = fmaf(a, w, acc[i]);
        }
    }
    if (valid) {
        #pragma unroll
        for (int i = 0; i < 16; ++i)
            out[(size_t)(b0 + i) * V + v] = acc[i];
    }
}

// ---------------------------------------------------------------------------
extern "C" void kernel_launch(void* const* d_in, const int* in_sizes, int n_in,
                              void* d_out, int out_size, void* d_ws, size_t ws_size,
                              hipStream_t stream) {
    const int*   token_ids = (const int*)d_in[0];
    const float* te        = (const float*)d_in[1];
    const float* pe        = (const float*)d_in[2];
    const float* q         = (const float*)d_in[3];
    const float* pos       = (const float*)d_in[4];
    const float* W         = (const float*)d_in[5];
    float*       out       = (float*)d_out;

    __hip_bfloat16* Abf = (__hip_bfloat16*)d_ws;                  // 1 MiB
    const size_t offW   = (size_t)B * K_PAD * sizeof(__hip_bfloat16);
    __hip_bfloat16* Wt  = (__hip_bfloat16*)((char*)d_ws + offW);  // ~12.9 MB
    const size_t need   = offW + (size_t)V_PAD * K_PAD * sizeof(__hip_bfloat16);

    ctx_act_kernel<<<dim3(B), dim3(256), 0, stream>>>(token_ids, te, pe, q, pos, Abf);

    if (ws_size >= need) {
        transpose_w<<<dim3(V_PAD / 256, 8), dim3(256), 0, stream>>>(W, Wt);
        gemm_mfma<<<dim3(V_PAD / 256, B / (MT * 16)), dim3(256), 0, stream>>>(Abf, Wt, out);
    } else {
        logits_fallback<<<dim3(V_PAD / 256, B / 16), dim3(256), 0, stream>>>(Abf, W, out);
    }
}

// Round 4
// 1131.054 us; speedup vs baseline: 1.4268x; 1.4268x over previous
//
#include <hip/hip_runtime.h>
#include <hip/hip_bf16.h>
#include <math.h>

#define B 4096
#define S 32
#define D 256
#define V 50257
#define N_ALIVE 100
#define K_PAD 128          // K=100 zero-padded to 128 (4 x mfma K=32)
#define V_PAD 50432        // 197 * 256

typedef __attribute__((ext_vector_type(8))) short short8;   // 8 bf16 (4 VGPRs)
typedef __attribute__((ext_vector_type(4))) float float4v;  // 4 fp32 acc

__device__ __forceinline__ short f2bf(float f) {
    __hip_bfloat16 h = __float2bfloat16(f);
    return *reinterpret_cast<short*>(&h);
}

// ---------------------------------------------------------------------------
// Kernel A: per-batch context pooling + RBF activations.
// Writes the bf16 A-matrix [B, K_PAD] (cols 100..127 zero).
// One block (256 threads = 4 waves) per batch row.
// ---------------------------------------------------------------------------
__global__ __launch_bounds__(256) void ctx_act_kernel(
    const int*   __restrict__ token_ids,   // [B,S]
    const float* __restrict__ te,          // [V,D]
    const float* __restrict__ pe,          // [S,D]
    const float* __restrict__ q,           // [D]
    const float* __restrict__ pos,         // [N,D]
    __hip_bfloat16* __restrict__ A)        // [B, K_PAD]
{
    __shared__ __align__(16) float s_emb[S][D];   // 32 KB
    __shared__ int   s_ids[S];
    __shared__ float s_scores[S];
    __shared__ float s_w[S];
    __shared__ __align__(16) float s_ctx[D];
    __shared__ float s_red[128];
    __shared__ float s_total;

    const int b    = blockIdx.x;
    const int tid  = threadIdx.x;
    const int lane = tid & 63;
    const int wave = tid >> 6;

    if (tid < S) s_ids[tid] = token_ids[b * S + tid];
    __syncthreads();

    // ---- embeds -> LDS + attention scores (wave w handles s = 8w..8w+7) ----
    const float4 qv = *(const float4*)(q + lane * 4);
    #pragma unroll
    for (int j = 0; j < 8; ++j) {
        const int s = wave * 8 + j;
        const float4 t4 = *(const float4*)(te + (size_t)s_ids[s] * D + lane * 4);
        const float4 p4 = *(const float4*)(pe + (size_t)s * D + lane * 4);
        float4 e4;
        e4.x = t4.x + p4.x; e4.y = t4.y + p4.y;
        e4.z = t4.z + p4.z; e4.w = t4.w + p4.w;
        *(float4*)&s_emb[s][lane * 4] = e4;
        float p = e4.x * qv.x + e4.y * qv.y + e4.z * qv.z + e4.w * qv.w;
        #pragma unroll
        for (int m = 32; m >= 1; m >>= 1) p += __shfl_xor(p, m);
        if (lane == 0) s_scores[s] = p * 0.0625f;   // 1/sqrt(256)
    }
    __syncthreads();

    // ---- softmax over S=32 (first 32 lanes of wave 0) ----
    if (tid < 32) {
        const float sc = s_scores[tid];
        float m = sc;
        #pragma unroll
        for (int k = 16; k >= 1; k >>= 1) m = fmaxf(m, __shfl_xor(m, k));
        const float e = expf(sc - m);
        float tot = e;
        #pragma unroll
        for (int k = 16; k >= 1; k >>= 1) tot += __shfl_xor(tot, k);
        s_w[tid] = e / tot;
    }
    __syncthreads();

    // ---- context: thread tid owns dim d = tid ----
    {
        float c = 0.f;
        #pragma unroll
        for (int s = 0; s < S; ++s) c += s_w[s] * s_emb[s][tid];
        s_ctx[tid] = c;
    }
    __syncthreads();

    // ---- RBF activations: thread n = tid (n < 100) ----
    float a = 0.f;
    if (tid < N_ALIVE) {
        const float4* p4 = (const float4*)(pos + (size_t)tid * D);
        const float4* c4 = (const float4*)s_ctx;
        float d2 = 0.f;
        #pragma unroll 8
        for (int dd = 0; dd < D / 4; ++dd) {
            const float4 cv = c4[dd];
            const float4 pv = p4[dd];
            const float dx = cv.x - pv.x;
            const float dy = cv.y - pv.y;
            const float dz = cv.z - pv.z;
            const float dw = cv.w - pv.w;
            d2 += dx * dx + dy * dy + dz * dz + dw * dw;
        }
        a = expf(-2.0f * d2);   // exp(-d2 / (2 * 0.5^2))
    }
    if (tid < 128) s_red[tid] = (tid < N_ALIVE) ? a : 0.f;
    __syncthreads();
    if (tid < 64) s_red[tid] += s_red[tid + 64];
    __syncthreads();
    if (tid < 64) {
        float v = s_red[tid];
        #pragma unroll
        for (int k = 32; k >= 1; k >>= 1) v += __shfl_xor(v, k);
        if (tid == 0) s_total = v;
    }
    __syncthreads();
    if (tid < K_PAD) {
        const float val = (tid < N_ALIVE) ? (a / (s_total + 1e-8f)) : 0.f;
        A[(size_t)b * K_PAD + tid] = __float2bfloat16(val);
    }
}

// ---------------------------------------------------------------------------
// Transpose/convert: Wt[v][k] = bf16(W[k][v]), zero-padded to [V_PAD, K_PAD].
// Coalesced W reads; stores packed into 2 x 16B per thread. grid = (197, 8).
// ---------------------------------------------------------------------------
__global__ __launch_bounds__(256) void transpose_w(
    const float* __restrict__ W,            // [N_ALIVE, V]
    __hip_bfloat16* __restrict__ Wt)        // [V_PAD, K_PAD]
{
    const int v  = blockIdx.x * 256 + threadIdx.x;   // < V_PAD by grid
    const int k0 = blockIdx.y * 16;
    short8 p0, p1;
    #pragma unroll
    for (int kk = 0; kk < 8; ++kk) {
        const int k = k0 + kk;
        p0[kk] = f2bf((v < V && k < N_ALIVE) ? W[(size_t)k * V + v] : 0.f);
    }
    #pragma unroll
    for (int kk = 0; kk < 8; ++kk) {
        const int k = k0 + 8 + kk;
        p1[kk] = f2bf((v < V && k < N_ALIVE) ? W[(size_t)k * V + v] : 0.f);
    }
    short* dst = (short*)Wt + (size_t)v * K_PAD + k0;   // 32B-aligned
    *(short8*)dst       = p0;
    *(short8*)(dst + 8) = p1;
}

// ---------------------------------------------------------------------------
// Kernel B: out[B,V] = A[B,K_PAD] @ Wt[V_PAD,K_PAD]^T via bf16 MFMA.
// Block = 256 threads (4 waves). Block tile: 64 M-rows x 256 N-cols.
// A-tile staged in LDS; low VGPR -> high occupancy. PLAIN stores (L2
// write-combining merges the 64B segments; R3's nontemporal stores caused
// 1.5x write + 0.5x fetch RMW amplification — 850us vs 140us floor).
// mfma_f32_16x16x32_bf16 layouts:
//   A: m = lane&15, k = (lane>>4)*8 + j
//   B: n = lane&15, k = (lane>>4)*8 + j
//   C/D: col = lane&15, row = (lane>>4)*4 + reg
// ---------------------------------------------------------------------------
#define MT 4
#define NITER 4
#define LDA 136   // shorts per LDS row (272B = 17*16B, keeps b128 aligned)

__global__ __launch_bounds__(256) void gemm_mfma(
    const __hip_bfloat16* __restrict__ A,    // [B, K_PAD]
    const __hip_bfloat16* __restrict__ Wt,   // [V_PAD, K_PAD]
    float* __restrict__ out)                 // [B, V]
{
    __shared__ __align__(16) short s_a[64 * LDA];   // 17 KB

    const int tid  = threadIdx.x;
    const int lane = tid & 63;
    const int wave = tid >> 6;
    const int quad = lane >> 4;
    const int l16  = lane & 15;
    const int y0   = blockIdx.y * (MT * 16);
    const int x0   = blockIdx.x * 256;

    // ---- stage A tile (64 rows x 256B) into LDS ----
    #pragma unroll
    for (int i = 0; i < 4; ++i) {
        const int idx  = i * 256 + tid;      // 0..1023
        const int row  = idx >> 4;           // 0..63
        const int chnk = idx & 15;           // 16B chunks
        const short8 vdat = *(const short8*)((const short*)A +
                              (size_t)(y0 + row) * K_PAD + chnk * 8);
        *(short8*)(s_a + row * LDA + chnk * 8) = vdat;
    }
    __syncthreads();

    for (int it = 0; it < NITER; ++it) {
        const int col = x0 + it * 64 + wave * 16 + l16;
        const short* bp = (const short*)Wt + (size_t)col * K_PAD;
        short8 b_frag[4];
        #pragma unroll
        for (int ks = 0; ks < 4; ++ks)
            b_frag[ks] = *(const short8*)(bp + ks * 32 + quad * 8);

        #pragma unroll
        for (int mt = 0; mt < MT; ++mt) {
            const short* ap = s_a + (mt * 16 + l16) * LDA + quad * 8;
            float4v acc = {0.f, 0.f, 0.f, 0.f};
            #pragma unroll
            for (int ks = 0; ks < 4; ++ks) {
                const short8 a_frag = *(const short8*)(ap + ks * 32);
                acc = __builtin_amdgcn_mfma_f32_16x16x32_bf16(
                          a_frag, b_frag[ks], acc, 0, 0, 0);
            }
            if (col < V) {
                #pragma unroll
                for (int r = 0; r < 4; ++r)
                    out[(size_t)(y0 + mt * 16 + quad * 4 + r) * V + col] = acc[r];
            }
        }
    }
}

// ---------------------------------------------------------------------------
// Fallback (ws too small for Wt): fp32 VALU, TB=16 rows in VGPRs (no spill).
// ---------------------------------------------------------------------------
__global__ __launch_bounds__(256) void logits_fallback(
    const __hip_bfloat16* __restrict__ A,   // [B, K_PAD]
    const float* __restrict__ W,            // [N_ALIVE, V]
    float* __restrict__ out)                // [B, V]
{
    const int v  = blockIdx.x * 256 + threadIdx.x;
    const int b0 = blockIdx.y * 16;
    const bool valid = (v < V);

    float acc[16];
    #pragma unroll
    for (int i = 0; i < 16; ++i) acc[i] = 0.f;

    for (int k = 0; k < N_ALIVE; ++k) {
        const float w = valid ? W[(size_t)k * V + v] : 0.f;
        #pragma unroll
        for (int i = 0; i < 16; ++i) {
            const float a = __bfloat162float(A[(size_t)(b0 + i) * K_PAD + k]);
            acc[i] = fmaf(a, w, acc[i]);
        }
    }
    if (valid) {
        #pragma unroll
        for (int i = 0; i < 16; ++i)
            out[(size_t)(b0 + i) * V + v] = acc[i];
    }
}

// ---------------------------------------------------------------------------
extern "C" void kernel_launch(void* const* d_in, const int* in_sizes, int n_in,
                              void* d_out, int out_size, void* d_ws, size_t ws_size,
                              hipStream_t stream) {
    const int*   token_ids = (const int*)d_in[0];
    const float* te        = (const float*)d_in[1];
    const float* pe        = (const float*)d_in[2];
    const float* q         = (const float*)d_in[3];
    const float* pos       = (const float*)d_in[4];
    const float* W         = (const float*)d_in[5];
    float*       out       = (float*)d_out;

    __hip_bfloat16* Abf = (__hip_bfloat16*)d_ws;                  // 1 MiB
    const size_t offW   = (size_t)B * K_PAD * sizeof(__hip_bfloat16);
    __hip_bfloat16* Wt  = (__hip_bfloat16*)((char*)d_ws + offW);  // ~12.9 MB
    const size_t need   = offW + (size_t)V_PAD * K_PAD * sizeof(__hip_bfloat16);

    ctx_act_kernel<<<dim3(B), dim3(256), 0, stream>>>(token_ids, te, pe, q, pos, Abf);

    if (ws_size >= need) {
        transpose_w<<<dim3(V_PAD / 256, 8), dim3(256), 0, stream>>>(W, Wt);
        gemm_mfma<<<dim3(V_PAD / 256, B / (MT * 16)), dim3(256), 0, stream>>>(Abf, Wt, out);
    } else {
        logits_fallback<<<dim3(V_PAD / 256, B / 16), dim3(256), 0, stream>>>(Abf, W, out);
    }
}